// Round 3
// baseline (1591.874 us; speedup 1.0000x reference)
//
#include <hip/hip_runtime.h>
#include <math.h>

// ---------------- problem constants ----------------
#define T_LEN   2880000      // samples per channel
#define LASTFR  5625         // frames t = 0..5625
#define NBLK_EQ 625          // 625 * 9 * 512 = 2,880,000
#define SCAN_B  1920         // scan segment (1500 segments/channel)
#define SCAN_L  30720        // scan warm-up (contraction e^-6.4)
#define SCAN_THREADS 3000

typedef float2 c2;
__device__ __forceinline__ c2 cadd(c2 a, c2 b){ return make_float2(a.x+b.x, a.y+b.y); }
__device__ __forceinline__ c2 csub(c2 a, c2 b){ return make_float2(a.x-b.x, a.y-b.y); }
__device__ __forceinline__ c2 cmul(c2 a, c2 b){ return make_float2(a.x*b.x - a.y*b.y, a.x*b.y + a.y*b.x); }
__device__ __forceinline__ c2 cmulj(c2 a, c2 b){ return make_float2(a.x*b.x + a.y*b.y, a.y*b.x - a.x*b.y); } // a*conj(b)

// 8-point DFT in registers. SGN=-1: forward; SGN=+1: inverse kernel (unnormalized).
template<int SGN>
__device__ __forceinline__ void dft8(c2 v[8]) {
    const float r = 0.70710678118654752f;
    c2 t0 = cadd(v[0], v[4]), t1 = csub(v[0], v[4]);
    c2 t2 = cadd(v[2], v[6]), t3 = csub(v[2], v[6]);
    c2 u0 = cadd(v[1], v[5]), u1 = csub(v[1], v[5]);
    c2 u2 = cadd(v[3], v[7]), u3 = csub(v[3], v[7]);
    c2 t3r = (SGN < 0) ? make_float2(t3.y, -t3.x) : make_float2(-t3.y, t3.x);
    c2 u3r = (SGN < 0) ? make_float2(u3.y, -u3.x) : make_float2(-u3.y, u3.x);
    c2 E0 = cadd(t0, t2), E2 = csub(t0, t2);
    c2 E1 = cadd(t1, t3r), E3 = csub(t1, t3r);
    c2 O0 = cadd(u0, u2), O2 = csub(u0, u2);
    c2 O1 = cadd(u1, u3r), O3 = csub(u1, u3r);
    c2 O1w = (SGN < 0) ? make_float2(r*(O1.x+O1.y), r*(O1.y-O1.x))
                       : make_float2(r*(O1.x-O1.y), r*(O1.x+O1.y));
    c2 O2w = (SGN < 0) ? make_float2(O2.y, -O2.x) : make_float2(-O2.y, O2.x);
    c2 O3w = (SGN < 0) ? make_float2(r*(O3.y-O3.x), -r*(O3.x+O3.y))
                       : make_float2(-r*(O3.x+O3.y), r*(O3.x-O3.y));
    v[0] = cadd(E0, O0);  v[4] = csub(E0, O0);
    v[1] = cadd(E1, O1w); v[5] = csub(E1, O1w);
    v[2] = cadd(E2, O2w); v[6] = csub(E2, O2w);
    v[3] = cadd(E3, O3w); v[7] = csub(E3, O3w);
}

__device__ __forceinline__ c2 shx(c2 v, int m) {
    return make_float2(__shfl_xor(v.x, m), __shfl_xor(v.y, m));
}

// emit one finished 512-sample chunk with wsum normalization.
// Interior chunks: sum of 4 hann^2 taps == 1.5 exactly (cos terms cancel, cos^2 sums to 2)
// -> inv = 2/3 constant; only chunks 2 (left edge) and 5626 (right edge) need the loop.
__device__ __forceinline__ void emit_chunk(float* __restrict__ dst, const float* __restrict__ WN,
                                           int cchunk, int tid, c2 r0, c2 r1) {
    const bool edge = (cchunk <= 2) || (cchunk >= 5626);
    #pragma unroll
    for (int q = 0; q < 2; ++q) {
        c2 rr = (q == 0) ? r0 : r1;
        int m = cchunk * 512 + (q << 8) + tid;
        float inv = 0.66666666666667f;
        if (edge) {
            int tmn = (m >= 2048) ? (((m - 2048) >> 9) + 1) : 0;
            int tmx = min(LASTFR, m >> 9);
            float wsum = 0.0f;
            for (int tt = tmn; tt <= tmx; ++tt) {
                float w = WN[m - (tt << 9)];
                wsum += w * w;
            }
            inv = (wsum > 1e-11f) ? (1.0f / wsum) : 1.0f;
        }
        int o = m - 1024;
        dst[o]         = rr.x * inv;
        dst[T_LEN + o] = rr.y * inv;
    }
}

// One EQ band: no-reorder fast convolution (verified R2).
__global__ __launch_bounds__(256) void eq_band_kernel(
    const float* __restrict__ src, float* __restrict__ dst,
    const float* __restrict__ gain_db_p, const float f0)
{
    __shared__ c2 SA[2048];
    __shared__ c2 TWs1[2048];
    __shared__ c2 TWs2[256];
    __shared__ c2 TWs3[32];
    __shared__ float MKs[2048];
    __shared__ float WN[2048];

    const int tid = threadIdx.x;
    const int b   = blockIdx.x;

    const float gdb   = *gain_db_p;
    const float g_lin = exp2f(gdb * 0.16609640474436813f);
    const float gm1   = g_lin - 1.0f;

    const float st2048 = 6.283185307179586f / 2048.0f;
    for (int idx = tid; idx < 2048; idx += 256) {
        int m = idx >> 8, j = idx & 255;
        float ang = st2048 * (float)(j * m);
        TWs1[idx] = make_float2(cosf(ang), -sinf(ang));
        WN[idx] = 0.5f - 0.5f * cosf(st2048 * (float)idx);
        int tt = idx & 255;
        int bb = tt >> 2, jj = tt & 3;
        int qrev = ((jj & 1) << 1) | (jj >> 1);
        int k = (bb >> 3) + ((bb & 7) << 3) + (m << 6) + (qrev << 9);
        int kk = (k > 1024) ? (2048 - k) : k;
        float f = (float)kk * (24000.0f / 1024.0f);
        float d = (f - f0) / f0;
        MKs[idx] = (1.0f + gm1 * expf(-d * d)) * (1.0f / 2048.0f);
    }
    {
        int m = tid >> 5, j2 = tid & 31;
        float ang = (6.283185307179586f / 256.0f) * (float)(j2 * m);
        TWs2[tid] = make_float2(cosf(ang), -sinf(ang));
    }
    if (tid < 32) {
        int m = tid >> 2, j = tid & 3;
        float ang = (6.283185307179586f / 32.0f) * (float)(j * m);
        TWs3[tid] = make_float2(cosf(ang), -sinf(ang));
    }
    __syncthreads();

    const int t0   = max(0, 9 * b - 1);
    const int t1   = min(LASTFR, 9 * b + 10);
    const int cmin = 9 * b + 2;
    const int cmax = 9 * b + 10;

    c2 ring[8];
    #pragma unroll
    for (int q = 0; q < 8; ++q) ring[q] = make_float2(0.0f, 0.0f);

    for (int t = t0; t <= t1; ++t) {
        for (int j = tid; j < 2048; j += 256) {
            int ss = t * 512 + j - 1024;
            ss = (ss < 0) ? -ss : ss;
            ss = (ss >= T_LEN) ? (2 * T_LEN - 2 - ss) : ss;
            float w = WN[j];
            SA[j] = make_float2(src[ss] * w, src[T_LEN + ss] * w);
        }
        __syncthreads();

        c2 v[8];

        // F1: radix-8, s=256
        #pragma unroll
        for (int k = 0; k < 8; ++k) v[k] = SA[tid + (k << 8)];
        dft8<-1>(v);
        #pragma unroll
        for (int m = 1; m < 8; ++m) v[m] = cmul(v[m], TWs1[(m << 8) + tid]);
        #pragma unroll
        for (int m = 0; m < 8; ++m) SA[tid + (m << 8)] = v[m];
        __syncthreads();

        // F2: radix-8, s=32, XOR-4 swizzled write
        {
            int c = tid >> 5, j2 = tid & 31;
            int base = (c << 8) + j2;
            #pragma unroll
            for (int k = 0; k < 8; ++k) v[k] = SA[base + (k << 5)];
            dft8<-1>(v);
            #pragma unroll
            for (int m = 1; m < 8; ++m) v[m] = cmul(v[m], TWs2[(m << 5) + j2]);
            __syncthreads();
            #pragma unroll
            for (int m = 0; m < 8; ++m) SA[(c << 8) + (m << 5) + (j2 ^ (m << 2))] = v[m];
        }
        __syncthreads();

        // F3 + F4(quad) + mask + I1(quad) + I2
        {
            int bb = tid >> 2, j = tid & 3;
            int base = bb << 5, bx = (bb & 7) << 2;
            #pragma unroll
            for (int k = 0; k < 8; ++k) v[k] = SA[base + ((k << 2) ^ bx) + j];
            dft8<-1>(v);
            #pragma unroll
            for (int m = 1; m < 8; ++m) v[m] = cmul(v[m], TWs3[(m << 2) + j]);
            #pragma unroll
            for (int m = 0; m < 8; ++m) {
                c2 w = v[m];
                c2 p = shx(w, 2);
                c2 e  = (j & 2) ? csub(p, w) : cadd(w, p);
                c2 qq = shx(e, 1);
                c2 lo = (j & 1) ? csub(qq, e) : cadd(e, qq);
                c2 hi = (j & 1) ? make_float2(qq.x - e.y, qq.y + e.x)
                                : make_float2(e.x + qq.y, e.y - qq.x);
                w = (j & 2) ? hi : lo;
                float mk = MKs[(m << 8) + tid];
                w.x *= mk; w.y *= mk;
                c2 p2 = shx(w, 1);
                c2 e2 = (j & 1) ? csub(p2, w) : cadd(w, p2);
                c2 q2 = shx(e2, 2);
                c2 lo2 = (j & 1) ? make_float2(e2.x - q2.y, e2.y + q2.x)
                                 : cadd(e2, q2);
                c2 hi2 = (j & 1) ? make_float2(q2.x + e2.y, q2.y - e2.x)
                                 : csub(q2, e2);
                v[m] = (j & 2) ? hi2 : lo2;
            }
            #pragma unroll
            for (int m = 1; m < 8; ++m) v[m] = cmulj(v[m], TWs3[(m << 2) + j]);
            dft8<+1>(v);
            __syncthreads();
            #pragma unroll
            for (int k = 0; k < 8; ++k) SA[base + ((k << 2) ^ bx) + j] = v[k];
        }
        __syncthreads();

        // I3
        {
            int c = tid >> 5, j2 = tid & 31;
            #pragma unroll
            for (int m = 0; m < 8; ++m) v[m] = SA[(c << 8) + (m << 5) + (j2 ^ (m << 2))];
            #pragma unroll
            for (int m = 1; m < 8; ++m) v[m] = cmulj(v[m], TWs2[(m << 5) + j2]);
            dft8<+1>(v);
            __syncthreads();
            #pragma unroll
            for (int k = 0; k < 8; ++k) SA[(c << 8) + (k << 5) + j2] = v[k];
        }
        __syncthreads();

        // I4 -> OLA ring
        {
            #pragma unroll
            for (int m = 0; m < 8; ++m) v[m] = SA[tid + (m << 8)];
            #pragma unroll
            for (int m = 1; m < 8; ++m) v[m] = cmulj(v[m], TWs1[(m << 8) + tid]);
            dft8<+1>(v);
            #pragma unroll
            for (int k = 0; k < 8; ++k) {
                float w = WN[tid + (k << 8)];
                ring[k].x += v[k].x * w;
                ring[k].y += v[k].y * w;
            }
        }
        __syncthreads();

        if (t >= cmin) emit_chunk(dst, WN, t, tid, ring[0], ring[1]);
        #pragma unroll
        for (int q = 0; q < 6; ++q) ring[q] = ring[q + 2];
        ring[6] = make_float2(0.0f, 0.0f);
        ring[7] = make_float2(0.0f, 0.0f);
    }
    for (int c = t1 + 1; c <= cmax; ++c) {
        emit_chunk(dst, WN, c, tid, ring[0], ring[1]);
        #pragma unroll
        for (int q = 0; q < 6; ++q) ring[q] = ring[q + 2];
        ring[6] = make_float2(0.0f, 0.0f);
        ring[7] = make_float2(0.0f, 0.0f);
    }
}

// per-sample gain-reduction * a_att
__global__ __launch_bounds__(256) void gr_kernel(
    const float* __restrict__ y, float* __restrict__ ga,
    const float* __restrict__ thr_p, const float* __restrict__ ratio_p,
    const float* __restrict__ att_p)
{
    int i = blockIdx.x * 256 + threadIdx.x;
    if (i >= 2 * T_LEN) return;
    float thr   = *thr_p;
    float ratio = *ratio_p;
    float a_att = 1.0f - expf(-1.0f / ((*att_p) * 48000.0f));
    float v  = y[i];
    float aa = fabsf(v) + 1e-8f;
    float adb = 6.020599913279624f * __log2f(aa);
    float gr  = fmaxf(adb - thr, 0.0f) * (1.0f - 1.0f / ratio);
    float gav = gr * a_att;
    if (i == 0 || i == T_LEN) gav = 0.0f;
    ga[i] = gav;
}

// ---------- scan: 6-slot register ring, no copy-out, no arrays ----------
// Slot = 16 samples (4 float4). Chain consumes slot components directly,
// stores in place, then refills the slot for i+80 (5-group prefetch distance
// ~= 800 cyc coverage; ~91% of lines are L2/LLC-warm per R2 FETCH_SIZE).
// Total loop-carried regs: 6*16 = 96 VGPR + ~20 misc -> no scratch spill.
struct Quad { float4 a, b, c, d; };

#define SCAN_STEP(x) { float vv = (x); \
    prev = fmaxf(fmaf(A, prev, vv), fmaf(B, prev, vv * ra)); (x) = prev; }

template<bool STORE>
__device__ __forceinline__ void scan_group(const float* __restrict__ g,
                                           float* __restrict__ out,
                                           Quad& s, int& i, float& prev,
                                           float A, float B, float ra)
{
    SCAN_STEP(s.a.x) SCAN_STEP(s.a.y) SCAN_STEP(s.a.z) SCAN_STEP(s.a.w)
    SCAN_STEP(s.b.x) SCAN_STEP(s.b.y) SCAN_STEP(s.b.z) SCAN_STEP(s.b.w)
    SCAN_STEP(s.c.x) SCAN_STEP(s.c.y) SCAN_STEP(s.c.z) SCAN_STEP(s.c.w)
    SCAN_STEP(s.d.x) SCAN_STEP(s.d.y) SCAN_STEP(s.d.z) SCAN_STEP(s.d.w)
    if (STORE) {
        *(float4*)(out + i)      = s.a;
        *(float4*)(out + i + 4)  = s.b;
        *(float4*)(out + i + 8)  = s.c;
        *(float4*)(out + i + 12) = s.d;
    }
    int pf = i + 80;                       // refill this slot, 5 groups ahead
    pf = (pf > T_LEN - 16) ? (T_LEN - 16) : pf;
    s.a = *(const float4*)(g + pf);
    s.b = *(const float4*)(g + pf + 4);
    s.c = *(const float4*)(g + pf + 8);
    s.d = *(const float4*)(g + pf + 12);
    i += 16;
}

__global__ __launch_bounds__(64, 1) void scan_kernel(
    const float* __restrict__ ga, float* __restrict__ gs,
    const float* __restrict__ att_p, const float* __restrict__ rel_p)
{
    int gid = blockIdx.x * 64 + threadIdx.x;
    if (gid >= SCAN_THREADS) return;               // 1500 segments x 2 channels
    int c   = gid / 1500;
    int blk = gid - c * 1500;
    const float* __restrict__ g  = ga + c * T_LEN;
    float* __restrict__ out      = gs + c * T_LEN;

    float A  = expf(-1.0f / ((*att_p) * 48000.0f));   // 1 - a_att
    float B  = expf(-1.0f / ((*rel_p) * 48000.0f));   // 1 - a_rel
    float ra = (1.0f - B) / (1.0f - A);               // a_rel / a_att

    int o0     = blk * SCAN_B;
    int wstart = max(0, o0 - SCAN_L);
    // warm groups = (o0-wstart)/16 is always a multiple of 6:
    //   full warm: 30720/16 = 1920 = 6*320 ; partial (blk<16): blk*120 = 6*(blk*20)
    int warm6 = ((o0 - wstart) >> 4) / 6;

    Quad r0, r1, r2, r3, r4, r5;
    {
        const float4* p = (const float4*)(g + wstart);
        r0.a = p[0];  r0.b = p[1];  r0.c = p[2];  r0.d = p[3];
        r1.a = p[4];  r1.b = p[5];  r1.c = p[6];  r1.d = p[7];
        r2.a = p[8];  r2.b = p[9];  r2.c = p[10]; r2.d = p[11];
        r3.a = p[12]; r3.b = p[13]; r3.c = p[14]; r3.d = p[15];
        r4.a = p[16]; r4.b = p[17]; r4.c = p[18]; r4.d = p[19];
        r5.a = p[20]; r5.b = p[21]; r5.c = p[22]; r5.d = p[23];
    }
    float prev = 0.0f;
    int i = wstart;

    for (int g6 = 0; g6 < warm6; ++g6) {
        scan_group<false>(g, out, r0, i, prev, A, B, ra);
        scan_group<false>(g, out, r1, i, prev, A, B, ra);
        scan_group<false>(g, out, r2, i, prev, A, B, ra);
        scan_group<false>(g, out, r3, i, prev, A, B, ra);
        scan_group<false>(g, out, r4, i, prev, A, B, ra);
        scan_group<false>(g, out, r5, i, prev, A, B, ra);
    }
    for (int g6 = 0; g6 < (SCAN_B / 16) / 6; ++g6) {  // 120/6 = 20
        scan_group<true>(g, out, r0, i, prev, A, B, ra);
        scan_group<true>(g, out, r1, i, prev, A, B, ra);
        scan_group<true>(g, out, r2, i, prev, A, B, ra);
        scan_group<true>(g, out, r3, i, prev, A, B, ra);
        scan_group<true>(g, out, r4, i, prev, A, B, ra);
        scan_group<true>(g, out, r5, i, prev, A, B, ra);
    }
}

// makeup/gain application + saturation
__global__ __launch_bounds__(256) void final_kernel(
    const float* __restrict__ y, float* __restrict__ io,
    const float* __restrict__ mk_p, const float* __restrict__ sat_p)
{
    int i = blockIdx.x * 256 + threadIdx.x;
    if (i >= 2 * T_LEN) return;
    float mk  = *mk_p;
    float sat = *sat_p;
    float v   = y[i];
    float gsv = io[i];
    float aa  = fabsf(v) + 1e-8f;
    float gl  = exp2f((mk - gsv) * 0.16609640474436813f);
    float r   = aa * gl;
    r = (v < 0.0f) ? -r : r;
    if (sat > 1.0f) r = tanhf(r * sat) / sat;
    io[i] = r;
}

extern "C" void kernel_launch(void* const* d_in, const int* in_sizes, int n_in,
                              void* d_out, int out_size, void* d_ws, size_t ws_size,
                              hipStream_t stream)
{
    const float* audio = (const float*)d_in[0];
    const float* g1    = (const float*)d_in[1];
    const float* g2    = (const float*)d_in[2];
    const float* g3    = (const float*)d_in[3];
    const float* g4    = (const float*)d_in[4];
    const float* thr   = (const float*)d_in[5];
    const float* ratio = (const float*)d_in[6];
    const float* att   = (const float*)d_in[7];
    const float* rel   = (const float*)d_in[8];
    const float* mkup  = (const float*)d_in[9];
    const float* sat   = (const float*)d_in[10];

    float* out  = (float*)d_out;
    float* bufA = (float*)d_ws;
    float* ga   = bufA + 2 * T_LEN;

    eq_band_kernel<<<NBLK_EQ, 256, 0, stream>>>(audio, out,  g1, 100.0f);
    eq_band_kernel<<<NBLK_EQ, 256, 0, stream>>>(out,   bufA, g2, 500.0f);
    eq_band_kernel<<<NBLK_EQ, 256, 0, stream>>>(bufA,  out,  g3, 3000.0f);
    eq_band_kernel<<<NBLK_EQ, 256, 0, stream>>>(out,   bufA, g4, 10000.0f);

    const int nel = 2 * T_LEN;
    gr_kernel<<<(nel + 255) / 256, 256, 0, stream>>>(bufA, ga, thr, ratio, att);
    scan_kernel<<<(SCAN_THREADS + 63) / 64, 64, 0, stream>>>(ga, out, att, rel);
    final_kernel<<<(nel + 255) / 256, 256, 0, stream>>>(bufA, out, mkup, sat);
}

// Round 4
// 1205.538 us; speedup vs baseline: 1.3205x; 1.3205x over previous
//
#include <hip/hip_runtime.h>
#include <math.h>

// ---------------- problem constants ----------------
#define T_LEN   2880000      // samples per channel
#define LASTFR  5625         // frames t = 0..5625
#define NBLK_EQ 625          // 625 * 9 * 512 = 2,880,000
#define NSEG    1500         // scan segments per channel
#define SEG     1920         // samples per segment (16 warm segments = 30720 warm-up)
#define PAIRS   960          // pair-steps per segment
#define STRIDE  1536         // transposed row stride (16 pad + 1500 + slack)
#define KG      20           // scan ring depth (pair-steps)

typedef float2 c2;
__device__ __forceinline__ c2 cadd(c2 a, c2 b){ return make_float2(a.x+b.x, a.y+b.y); }
__device__ __forceinline__ c2 csub(c2 a, c2 b){ return make_float2(a.x-b.x, a.y-b.y); }
__device__ __forceinline__ c2 cmul(c2 a, c2 b){ return make_float2(a.x*b.x - a.y*b.y, a.x*b.y + a.y*b.x); }
__device__ __forceinline__ c2 cmulj(c2 a, c2 b){ return make_float2(a.x*b.x + a.y*b.y, a.y*b.x - a.x*b.y); }

template<int SGN>
__device__ __forceinline__ void dft8(c2 v[8]) {
    const float r = 0.70710678118654752f;
    c2 t0 = cadd(v[0], v[4]), t1 = csub(v[0], v[4]);
    c2 t2 = cadd(v[2], v[6]), t3 = csub(v[2], v[6]);
    c2 u0 = cadd(v[1], v[5]), u1 = csub(v[1], v[5]);
    c2 u2 = cadd(v[3], v[7]), u3 = csub(v[3], v[7]);
    c2 t3r = (SGN < 0) ? make_float2(t3.y, -t3.x) : make_float2(-t3.y, t3.x);
    c2 u3r = (SGN < 0) ? make_float2(u3.y, -u3.x) : make_float2(-u3.y, u3.x);
    c2 E0 = cadd(t0, t2), E2 = csub(t0, t2);
    c2 E1 = cadd(t1, t3r), E3 = csub(t1, t3r);
    c2 O0 = cadd(u0, u2), O2 = csub(u0, u2);
    c2 O1 = cadd(u1, u3r), O3 = csub(u1, u3r);
    c2 O1w = (SGN < 0) ? make_float2(r*(O1.x+O1.y), r*(O1.y-O1.x))
                       : make_float2(r*(O1.x-O1.y), r*(O1.x+O1.y));
    c2 O2w = (SGN < 0) ? make_float2(O2.y, -O2.x) : make_float2(-O2.y, O2.x);
    c2 O3w = (SGN < 0) ? make_float2(r*(O3.y-O3.x), -r*(O3.x+O3.y))
                       : make_float2(-r*(O3.x+O3.y), r*(O3.x-O3.y));
    v[0] = cadd(E0, O0);  v[4] = csub(E0, O0);
    v[1] = cadd(E1, O1w); v[5] = csub(E1, O1w);
    v[2] = cadd(E2, O2w); v[6] = csub(E2, O2w);
    v[3] = cadd(E3, O3w); v[7] = csub(E3, O3w);
}

__device__ __forceinline__ c2 shx(c2 v, int m) {
    return make_float2(__shfl_xor(v.x, m), __shfl_xor(v.y, m));
}

// interior chunks: wsum == 1.5 exactly; only edges need the loop
__device__ __forceinline__ void emit_chunk(float* __restrict__ dst, const float* __restrict__ WN,
                                           int cchunk, int tid, c2 r0, c2 r1) {
    const bool edge = (cchunk <= 2) || (cchunk >= 5626);
    #pragma unroll
    for (int q = 0; q < 2; ++q) {
        c2 rr = (q == 0) ? r0 : r1;
        int m = cchunk * 512 + (q << 8) + tid;
        float inv = 0.66666666666667f;
        if (edge) {
            int tmn = (m >= 2048) ? (((m - 2048) >> 9) + 1) : 0;
            int tmx = min(LASTFR, m >> 9);
            float wsum = 0.0f;
            for (int tt = tmn; tt <= tmx; ++tt) {
                float w = WN[m - (tt << 9)];
                wsum += w * w;
            }
            inv = (wsum > 1e-11f) ? (1.0f / wsum) : 1.0f;
        }
        int o = m - 1024;
        dst[o]         = rr.x * inv;
        dst[T_LEN + o] = rr.y * inv;
    }
}

// One EQ band: no-reorder fast convolution (verified R2).
__global__ __launch_bounds__(256) void eq_band_kernel(
    const float* __restrict__ src, float* __restrict__ dst,
    const float* __restrict__ gain_db_p, const float f0)
{
    __shared__ c2 SA[2048];
    __shared__ c2 TWs1[2048];
    __shared__ c2 TWs2[256];
    __shared__ c2 TWs3[32];
    __shared__ float MKs[2048];
    __shared__ float WN[2048];

    const int tid = threadIdx.x;
    const int b   = blockIdx.x;

    const float gdb   = *gain_db_p;
    const float g_lin = exp2f(gdb * 0.16609640474436813f);
    const float gm1   = g_lin - 1.0f;

    const float st2048 = 6.283185307179586f / 2048.0f;
    for (int idx = tid; idx < 2048; idx += 256) {
        int m = idx >> 8, j = idx & 255;
        float ang = st2048 * (float)(j * m);
        TWs1[idx] = make_float2(cosf(ang), -sinf(ang));
        WN[idx] = 0.5f - 0.5f * cosf(st2048 * (float)idx);
        int tt = idx & 255;
        int bb = tt >> 2, jj = tt & 3;
        int qrev = ((jj & 1) << 1) | (jj >> 1);
        int k = (bb >> 3) + ((bb & 7) << 3) + (m << 6) + (qrev << 9);
        int kk = (k > 1024) ? (2048 - k) : k;
        float f = (float)kk * (24000.0f / 1024.0f);
        float d = (f - f0) / f0;
        MKs[idx] = (1.0f + gm1 * expf(-d * d)) * (1.0f / 2048.0f);
    }
    {
        int m = tid >> 5, j2 = tid & 31;
        float ang = (6.283185307179586f / 256.0f) * (float)(j2 * m);
        TWs2[tid] = make_float2(cosf(ang), -sinf(ang));
    }
    if (tid < 32) {
        int m = tid >> 2, j = tid & 3;
        float ang = (6.283185307179586f / 32.0f) * (float)(j * m);
        TWs3[tid] = make_float2(cosf(ang), -sinf(ang));
    }
    __syncthreads();

    const int t0   = max(0, 9 * b - 1);
    const int t1   = min(LASTFR, 9 * b + 10);
    const int cmin = 9 * b + 2;
    const int cmax = 9 * b + 10;

    c2 ring[8];
    #pragma unroll
    for (int q = 0; q < 8; ++q) ring[q] = make_float2(0.0f, 0.0f);

    for (int t = t0; t <= t1; ++t) {
        for (int j = tid; j < 2048; j += 256) {
            int ss = t * 512 + j - 1024;
            ss = (ss < 0) ? -ss : ss;
            ss = (ss >= T_LEN) ? (2 * T_LEN - 2 - ss) : ss;
            float w = WN[j];
            SA[j] = make_float2(src[ss] * w, src[T_LEN + ss] * w);
        }
        __syncthreads();

        c2 v[8];

        // F1
        #pragma unroll
        for (int k = 0; k < 8; ++k) v[k] = SA[tid + (k << 8)];
        dft8<-1>(v);
        #pragma unroll
        for (int m = 1; m < 8; ++m) v[m] = cmul(v[m], TWs1[(m << 8) + tid]);
        #pragma unroll
        for (int m = 0; m < 8; ++m) SA[tid + (m << 8)] = v[m];
        __syncthreads();

        // F2
        {
            int c = tid >> 5, j2 = tid & 31;
            int base = (c << 8) + j2;
            #pragma unroll
            for (int k = 0; k < 8; ++k) v[k] = SA[base + (k << 5)];
            dft8<-1>(v);
            #pragma unroll
            for (int m = 1; m < 8; ++m) v[m] = cmul(v[m], TWs2[(m << 5) + j2]);
            __syncthreads();
            #pragma unroll
            for (int m = 0; m < 8; ++m) SA[(c << 8) + (m << 5) + (j2 ^ (m << 2))] = v[m];
        }
        __syncthreads();

        // F3 + F4(quad) + mask + I1(quad) + I2
        {
            int bb = tid >> 2, j = tid & 3;
            int base = bb << 5, bx = (bb & 7) << 2;
            #pragma unroll
            for (int k = 0; k < 8; ++k) v[k] = SA[base + ((k << 2) ^ bx) + j];
            dft8<-1>(v);
            #pragma unroll
            for (int m = 1; m < 8; ++m) v[m] = cmul(v[m], TWs3[(m << 2) + j]);
            #pragma unroll
            for (int m = 0; m < 8; ++m) {
                c2 w = v[m];
                c2 p = shx(w, 2);
                c2 e  = (j & 2) ? csub(p, w) : cadd(w, p);
                c2 qq = shx(e, 1);
                c2 lo = (j & 1) ? csub(qq, e) : cadd(e, qq);
                c2 hi = (j & 1) ? make_float2(qq.x - e.y, qq.y + e.x)
                                : make_float2(e.x + qq.y, e.y - qq.x);
                w = (j & 2) ? hi : lo;
                float mk = MKs[(m << 8) + tid];
                w.x *= mk; w.y *= mk;
                c2 p2 = shx(w, 1);
                c2 e2 = (j & 1) ? csub(p2, w) : cadd(w, p2);
                c2 q2 = shx(e2, 2);
                c2 lo2 = (j & 1) ? make_float2(e2.x - q2.y, e2.y + q2.x)
                                 : cadd(e2, q2);
                c2 hi2 = (j & 1) ? make_float2(q2.x + e2.y, q2.y - e2.x)
                                 : csub(q2, e2);
                v[m] = (j & 2) ? hi2 : lo2;
            }
            #pragma unroll
            for (int m = 1; m < 8; ++m) v[m] = cmulj(v[m], TWs3[(m << 2) + j]);
            dft8<+1>(v);
            __syncthreads();
            #pragma unroll
            for (int k = 0; k < 8; ++k) SA[base + ((k << 2) ^ bx) + j] = v[k];
        }
        __syncthreads();

        // I3
        {
            int c = tid >> 5, j2 = tid & 31;
            #pragma unroll
            for (int m = 0; m < 8; ++m) v[m] = SA[(c << 8) + (m << 5) + (j2 ^ (m << 2))];
            #pragma unroll
            for (int m = 1; m < 8; ++m) v[m] = cmulj(v[m], TWs2[(m << 5) + j2]);
            dft8<+1>(v);
            __syncthreads();
            #pragma unroll
            for (int k = 0; k < 8; ++k) SA[(c << 8) + (k << 5) + j2] = v[k];
        }
        __syncthreads();

        // I4 -> OLA ring
        {
            #pragma unroll
            for (int m = 0; m < 8; ++m) v[m] = SA[tid + (m << 8)];
            #pragma unroll
            for (int m = 1; m < 8; ++m) v[m] = cmulj(v[m], TWs1[(m << 8) + tid]);
            dft8<+1>(v);
            #pragma unroll
            for (int k = 0; k < 8; ++k) {
                float w = WN[tid + (k << 8)];
                ring[k].x += v[k].x * w;
                ring[k].y += v[k].y * w;
            }
        }
        __syncthreads();

        if (t >= cmin) emit_chunk(dst, WN, t, tid, ring[0], ring[1]);
        #pragma unroll
        for (int q = 0; q < 6; ++q) ring[q] = ring[q + 2];
        ring[6] = make_float2(0.0f, 0.0f);
        ring[7] = make_float2(0.0f, 0.0f);
    }
    for (int c = t1 + 1; c <= cmax; ++c) {
        emit_chunk(dst, WN, c, tid, ring[0], ring[1]);
        #pragma unroll
        for (int q = 0; q < 6; ++q) ring[q] = ring[q + 2];
        ring[6] = make_float2(0.0f, 0.0f);
        ring[7] = make_float2(0.0f, 0.0f);
    }
}

// ---------- pair-record producer: gr + 2-step intercepts + LDS transpose ----------
// Records for pair (a1,a2) with b=ra*a:  I1 = A*a1+a2 ; I2 = max(A*ra*a1+a2, B*a1+ra*a2) ;
// I3 = ra*(B*a1+a2).  Scan then does p' = max3(AA*p+I1, AB*p+I2, BB*p+I3)  (== 2 reference steps).
// Transposed layout: plane[row=pair][col=16+seg], row stride 1536, 16 zero pad cols for warm-up.
__global__ __launch_bounds__(256) void pair_kernel(
    const float* __restrict__ y, float2* __restrict__ plA, float* __restrict__ plB,
    const float* __restrict__ thr_p, const float* __restrict__ ratio_p,
    const float* __restrict__ att_p, const float* __restrict__ rel_p)
{
    __shared__ float2 L[64][65];
    const int s0  = blockIdx.x * 64;
    const int pr0 = blockIdx.y * 64;
    const int c   = blockIdx.z;
    const int tid = threadIdx.x;

    float thr = *thr_p, ratio = *ratio_p;
    float A  = expf(-1.0f / ((*att_p) * 48000.0f));
    float Bc = expf(-1.0f / ((*rel_p) * 48000.0f));
    float ra = (1.0f - Bc) / (1.0f - A);
    float coef = (1.0f - 1.0f / ratio) * (1.0f - A);   // (1-1/r)*a_att

    const int j0 = pr0 * 2;
    for (int it = 0; it < 32; ++it) {
        int idx = it * 256 + tid;
        int ss = idx >> 7, jj = idx & 127;
        int s = s0 + ss;
        float gav = 0.0f;
        if (s < NSEG) {
            int li = s * SEG + j0 + jj;
            float v = y[c * T_LEN + li];
            float aa = fabsf(v) + 1e-8f;
            float adb = 6.020599913279624f * __log2f(aa);
            gav = fmaxf(adb - thr, 0.0f) * coef;
            if (li == 0) gav = 0.0f;               // exact i=0 boundary
        }
        ((float*)&L[ss][0])[jj] = gav;
    }
    __syncthreads();

    for (int it = 0; it < 16; ++it) {
        int idx = it * 256 + tid;
        int ss = idx & 63, pr = idx >> 6;
        if (s0 + ss < NSEG) {
            float2 a = L[ss][pr];                  // (a1, a2)
            float i1 = fmaf(A, a.x, a.y);
            float i2 = fmaxf(fmaf(A * ra, a.x, a.y), fmaf(Bc, a.x, ra * a.y));
            float i3 = ra * fmaf(Bc, a.x, a.y);
            long off = (long)c * PAIRS * STRIDE + (long)(pr0 + pr) * STRIDE + 16 + s0 + ss;
            plA[off] = make_float2(i1, i2);
            plB[off] = i3;
        }
    }
}

// zero the 16 warm-up pad columns (ws is poisoned 0xAA each call)
__global__ __launch_bounds__(256) void padzero_kernel(float2* __restrict__ plA,
                                                      float* __restrict__ plB)
{
    int idx = blockIdx.x * 256 + threadIdx.x;
    if (idx >= 2 * PAIRS * 16) return;
    int ch = idx / (PAIRS * 16);
    int r  = (idx >> 4) % PAIRS;
    int col = idx & 15;
    long off = (long)ch * PAIRS * STRIDE + (long)r * STRIDE + col;
    plA[off] = make_float2(0.0f, 0.0f);
    plB[off] = 0.0f;
}

// ---------- scan: coalesced transposed reads, 20-deep pair ring ----------
// Lane = segment. Thread s consumes cols s..s+16 (16 warm segs incl. zero pads + own).
// Stores only odd-sample states (one per pair) to gsP; final_kernel recomputes evens.
__global__ __launch_bounds__(64, 1) void scan_kernel(
    const float2* __restrict__ plA, const float* __restrict__ plB,
    float* __restrict__ gsP,
    const float* __restrict__ att_p, const float* __restrict__ rel_p)
{
    int gid = blockIdx.x * 64 + threadIdx.x;      // 48 blocks; 1536 lanes/channel
    int c = gid / 1536;
    int s = gid - c * 1536;
    s = min(s, NSEG - 1);                          // dup lanes: harmless identical work

    const float2* baseA = plA + (long)c * PAIRS * STRIDE;
    const float*  baseB = plB + (long)c * PAIRS * STRIDE;
    float* outP = gsP + (c * NSEG + s) * PAIRS;

    float A  = expf(-1.0f / ((*att_p) * 48000.0f));
    float Bc = expf(-1.0f / ((*rel_p) * 48000.0f));
    float AA = A * A, AB = A * Bc, BB = Bc * Bc;

    float2 rA[KG]; float rB[KG];
    {
        const float2* pa = baseA + s;
        const float*  pb = baseB + s;
        #pragma unroll
        for (int k = 0; k < KG; ++k) { rA[k] = pa[k * STRIDE]; rB[k] = pb[k * STRIDE]; }
    }
    float p = 0.0f;

    // 16 warm segments (first ones read zero pads -> exact)
    for (int seg = 0; seg < 16; ++seg) {
        const float2* pa = baseA + (s + seg) + KG * STRIDE;
        const float*  pb = baseB + (s + seg) + KG * STRIDE;
        for (int g = 0; g < 47; ++g) {
            #pragma unroll
            for (int k = 0; k < KG; ++k) {
                p = fmaxf(fmaxf(fmaf(AA, p, rA[k].x), fmaf(AB, p, rA[k].y)),
                          fmaf(BB, p, rB[k]));
                rA[k] = pa[k * STRIDE]; rB[k] = pb[k * STRIDE];
            }
            pa += KG * STRIDE; pb += KG * STRIDE;
        }
        const float2* pa2 = baseA + (s + seg + 1);   // next col rows 0..19
        const float*  pb2 = baseB + (s + seg + 1);
        #pragma unroll
        for (int k = 0; k < KG; ++k) {
            p = fmaxf(fmaxf(fmaf(AA, p, rA[k].x), fmaf(AB, p, rA[k].y)),
                      fmaf(BB, p, rB[k]));
            rA[k] = pa2[k * STRIDE]; rB[k] = pb2[k * STRIDE];
        }
    }
    // own segment: consume + store odd states
    {
        const float2* pa = baseA + (s + 16) + KG * STRIDE;
        const float*  pb = baseB + (s + 16) + KG * STRIDE;
        float4 acc;
        for (int g = 0; g < 47; ++g) {
            #pragma unroll
            for (int k = 0; k < KG; ++k) {
                p = fmaxf(fmaxf(fmaf(AA, p, rA[k].x), fmaf(AB, p, rA[k].y)),
                          fmaf(BB, p, rB[k]));
                ((float*)&acc)[k & 3] = p;
                if ((k & 3) == 3) *(float4*)(outP + g * KG + k - 3) = acc;
                rA[k] = pa[k * STRIDE]; rB[k] = pb[k * STRIDE];
            }
            pa += KG * STRIDE; pb += KG * STRIDE;
        }
        #pragma unroll
        for (int k = 0; k < KG; ++k) {               // last group, no refill
            p = fmaxf(fmaxf(fmaf(AA, p, rA[k].x), fmaf(AB, p, rA[k].y)),
                      fmaf(BB, p, rB[k]));
            ((float*)&acc)[k & 3] = p;
            if ((k & 3) == 3) *(float4*)(outP + 940 + k - 3) = acc;
        }
    }
}

// ---------- final: reconstruct even states + makeup + saturation ----------
__global__ __launch_bounds__(256) void final_kernel(
    const float* __restrict__ y, const float* __restrict__ gsP, float* __restrict__ out,
    const float* __restrict__ thr_p, const float* __restrict__ ratio_p,
    const float* __restrict__ att_p, const float* __restrict__ rel_p,
    const float* __restrict__ mk_p, const float* __restrict__ sat_p)
{
    int k = blockIdx.x * 256 + threadIdx.x;
    if (k >= T_LEN) return;                        // T_LEN pairs total (both channels)
    int c = (k >= T_LEN / 2);
    int local = k - c * (T_LEN / 2);
    int i0 = c * T_LEN + 2 * local;

    float thr = *thr_p, ratio = *ratio_p, mk = *mk_p, sat = *sat_p;
    float A  = expf(-1.0f / ((*att_p) * 48000.0f));
    float Bc = expf(-1.0f / ((*rel_p) * 48000.0f));
    float ra = (1.0f - Bc) / (1.0f - A);
    float coef = (1.0f - 1.0f / ratio) * (1.0f - A);

    float p1 = gsP[k];
    float p0 = (local == 0) ? 0.0f : gsP[k - 1];
    float2 yv = *(const float2*)(y + i0);

    float aa0 = fabsf(yv.x) + 1e-8f;
    float gav0 = fmaxf(6.020599913279624f * __log2f(aa0) - thr, 0.0f) * coef;
    if (local == 0) gav0 = 0.0f;
    float pe = fmaxf(fmaf(A, p0, gav0), fmaf(Bc, p0, gav0 * ra));  // even-sample state

    float aa1 = fabsf(yv.y) + 1e-8f;
    float gl0 = exp2f((mk - pe) * 0.16609640474436813f);
    float gl1 = exp2f((mk - p1) * 0.16609640474436813f);
    float r0 = aa0 * gl0; r0 = (yv.x < 0.0f) ? -r0 : r0;
    float r1 = aa1 * gl1; r1 = (yv.y < 0.0f) ? -r1 : r1;
    if (sat > 1.0f) { r0 = tanhf(r0 * sat) / sat; r1 = tanhf(r1 * sat) / sat; }
    *(float2*)(out + i0) = make_float2(r0, r1);
}

extern "C" void kernel_launch(void* const* d_in, const int* in_sizes, int n_in,
                              void* d_out, int out_size, void* d_ws, size_t ws_size,
                              hipStream_t stream)
{
    const float* audio = (const float*)d_in[0];
    const float* g1    = (const float*)d_in[1];
    const float* g2    = (const float*)d_in[2];
    const float* g3    = (const float*)d_in[3];
    const float* g4    = (const float*)d_in[4];
    const float* thr   = (const float*)d_in[5];
    const float* ratio = (const float*)d_in[6];
    const float* att   = (const float*)d_in[7];
    const float* rel   = (const float*)d_in[8];
    const float* mkup  = (const float*)d_in[9];
    const float* sat   = (const float*)d_in[10];

    float* out  = (float*)d_out;                      // EQ ping-pong
    float* bufA = (float*)d_ws;                       // 2T floats = 23.04 MB
    float2* plA = (float2*)(bufA + 2 * T_LEN);        // 2*960*1536 float2 = 23.6 MB
    float*  plB = (float*)(plA + 2 * PAIRS * STRIDE); // 2*960*1536 float  = 11.8 MB
    float*  gsP = plB + 2 * PAIRS * STRIDE;           // 2*1.44M floats    = 11.5 MB
                                                      // total ws use ~70 MB

    eq_band_kernel<<<NBLK_EQ, 256, 0, stream>>>(audio, out,  g1, 100.0f);
    eq_band_kernel<<<NBLK_EQ, 256, 0, stream>>>(out,   bufA, g2, 500.0f);
    eq_band_kernel<<<NBLK_EQ, 256, 0, stream>>>(bufA,  out,  g3, 3000.0f);
    eq_band_kernel<<<NBLK_EQ, 256, 0, stream>>>(out,   bufA, g4, 10000.0f);

    dim3 pgrid(24, 15, 2);                            // 64-seg x 64-pair tiles
    pair_kernel<<<pgrid, 256, 0, stream>>>(bufA, plA, plB, thr, ratio, att, rel);
    padzero_kernel<<<(2 * PAIRS * 16 + 255) / 256, 256, 0, stream>>>(plA, plB);
    scan_kernel<<<48, 64, 0, stream>>>(plA, plB, gsP, att, rel);
    final_kernel<<<(T_LEN + 255) / 256, 256, 0, stream>>>(bufA, gsP, out,
                                                          thr, ratio, att, rel, mkup, sat);
}

// Round 5
// 791.684 us; speedup vs baseline: 2.0107x; 1.5228x over previous
//
#include <hip/hip_runtime.h>
#include <math.h>

// ---------------- problem constants ----------------
#define T_LEN   2880000      // samples per channel
#define LASTFR  5625         // frames t = 0..5625
#define NBLK_EQ 625          // 625 * 9 * 512 = 2,880,000
#define SEG     7680         // scan segment samples
#define NSEG    375          // segments per channel
#define RECS    2560         // K=3 records per segment
#define ROWSA   2576         // rows allocated (16 junk rows for prefetch overrun)
#define RST     384          // record-plane row stride (4 pad cols + 375 + slack)
#define PLANE   (ROWSA * RST)    // float4 elems per channel plane
#define SPLANE  (RECS * RST)     // float elems per channel state plane

typedef float2 c2;
__device__ __forceinline__ c2 cadd(c2 a, c2 b){ return make_float2(a.x+b.x, a.y+b.y); }
__device__ __forceinline__ c2 csub(c2 a, c2 b){ return make_float2(a.x-b.x, a.y-b.y); }
__device__ __forceinline__ c2 cmul(c2 a, c2 b){ return make_float2(a.x*b.x - a.y*b.y, a.x*b.y + a.y*b.x); }
__device__ __forceinline__ c2 cmulj(c2 a, c2 b){ return make_float2(a.x*b.x + a.y*b.y, a.y*b.x - a.x*b.y); }

template<int SGN>
__device__ __forceinline__ void dft8(c2 v[8]) {
    const float r = 0.70710678118654752f;
    c2 t0 = cadd(v[0], v[4]), t1 = csub(v[0], v[4]);
    c2 t2 = cadd(v[2], v[6]), t3 = csub(v[2], v[6]);
    c2 u0 = cadd(v[1], v[5]), u1 = csub(v[1], v[5]);
    c2 u2 = cadd(v[3], v[7]), u3 = csub(v[3], v[7]);
    c2 t3r = (SGN < 0) ? make_float2(t3.y, -t3.x) : make_float2(-t3.y, t3.x);
    c2 u3r = (SGN < 0) ? make_float2(u3.y, -u3.x) : make_float2(-u3.y, u3.x);
    c2 E0 = cadd(t0, t2), E2 = csub(t0, t2);
    c2 E1 = cadd(t1, t3r), E3 = csub(t1, t3r);
    c2 O0 = cadd(u0, u2), O2 = csub(u0, u2);
    c2 O1 = cadd(u1, u3r), O3 = csub(u1, u3r);
    c2 O1w = (SGN < 0) ? make_float2(r*(O1.x+O1.y), r*(O1.y-O1.x))
                       : make_float2(r*(O1.x-O1.y), r*(O1.x+O1.y));
    c2 O2w = (SGN < 0) ? make_float2(O2.y, -O2.x) : make_float2(-O2.y, O2.x);
    c2 O3w = (SGN < 0) ? make_float2(r*(O3.y-O3.x), -r*(O3.x+O3.y))
                       : make_float2(-r*(O3.x+O3.y), r*(O3.x-O3.y));
    v[0] = cadd(E0, O0);  v[4] = csub(E0, O0);
    v[1] = cadd(E1, O1w); v[5] = csub(E1, O1w);
    v[2] = cadd(E2, O2w); v[6] = csub(E2, O2w);
    v[3] = cadd(E3, O3w); v[7] = csub(E3, O3w);
}

__device__ __forceinline__ c2 shx(c2 v, int m) {
    return make_float2(__shfl_xor(v.x, m), __shfl_xor(v.y, m));
}

__device__ __forceinline__ void emit_chunk(float* __restrict__ dst, const float* __restrict__ WN,
                                           int cchunk, int tid, c2 r0, c2 r1) {
    const bool edge = (cchunk <= 2) || (cchunk >= 5626);
    #pragma unroll
    for (int q = 0; q < 2; ++q) {
        c2 rr = (q == 0) ? r0 : r1;
        int m = cchunk * 512 + (q << 8) + tid;
        float inv = 0.66666666666667f;
        if (edge) {
            int tmn = (m >= 2048) ? (((m - 2048) >> 9) + 1) : 0;
            int tmx = min(LASTFR, m >> 9);
            float wsum = 0.0f;
            for (int tt = tmn; tt <= tmx; ++tt) {
                float w = WN[m - (tt << 9)];
                wsum += w * w;
            }
            inv = (wsum > 1e-11f) ? (1.0f / wsum) : 1.0f;
        }
        int o = m - 1024;
        dst[o]         = rr.x * inv;
        dst[T_LEN + o] = rr.y * inv;
    }
}

// One EQ band: no-reorder fast convolution (verified R2).
__global__ __launch_bounds__(256) void eq_band_kernel(
    const float* __restrict__ src, float* __restrict__ dst,
    const float* __restrict__ gain_db_p, const float f0)
{
    __shared__ c2 SA[2048];
    __shared__ c2 TWs1[2048];
    __shared__ c2 TWs2[256];
    __shared__ c2 TWs3[32];
    __shared__ float MKs[2048];
    __shared__ float WN[2048];

    const int tid = threadIdx.x;
    const int b   = blockIdx.x;

    const float gdb   = *gain_db_p;
    const float g_lin = exp2f(gdb * 0.16609640474436813f);
    const float gm1   = g_lin - 1.0f;

    const float st2048 = 6.283185307179586f / 2048.0f;
    for (int idx = tid; idx < 2048; idx += 256) {
        int m = idx >> 8, j = idx & 255;
        float ang = st2048 * (float)(j * m);
        TWs1[idx] = make_float2(cosf(ang), -sinf(ang));
        WN[idx] = 0.5f - 0.5f * cosf(st2048 * (float)idx);
        int tt = idx & 255;
        int bb = tt >> 2, jj = tt & 3;
        int qrev = ((jj & 1) << 1) | (jj >> 1);
        int k = (bb >> 3) + ((bb & 7) << 3) + (m << 6) + (qrev << 9);
        int kk = (k > 1024) ? (2048 - k) : k;
        float f = (float)kk * (24000.0f / 1024.0f);
        float d = (f - f0) / f0;
        MKs[idx] = (1.0f + gm1 * expf(-d * d)) * (1.0f / 2048.0f);
    }
    {
        int m = tid >> 5, j2 = tid & 31;
        float ang = (6.283185307179586f / 256.0f) * (float)(j2 * m);
        TWs2[tid] = make_float2(cosf(ang), -sinf(ang));
    }
    if (tid < 32) {
        int m = tid >> 2, j = tid & 3;
        float ang = (6.283185307179586f / 32.0f) * (float)(j * m);
        TWs3[tid] = make_float2(cosf(ang), -sinf(ang));
    }
    __syncthreads();

    const int t0   = max(0, 9 * b - 1);
    const int t1   = min(LASTFR, 9 * b + 10);
    const int cmin = 9 * b + 2;
    const int cmax = 9 * b + 10;

    c2 ring[8];
    #pragma unroll
    for (int q = 0; q < 8; ++q) ring[q] = make_float2(0.0f, 0.0f);

    for (int t = t0; t <= t1; ++t) {
        for (int j = tid; j < 2048; j += 256) {
            int ss = t * 512 + j - 1024;
            ss = (ss < 0) ? -ss : ss;
            ss = (ss >= T_LEN) ? (2 * T_LEN - 2 - ss) : ss;
            float w = WN[j];
            SA[j] = make_float2(src[ss] * w, src[T_LEN + ss] * w);
        }
        __syncthreads();

        c2 v[8];

        // F1
        #pragma unroll
        for (int k = 0; k < 8; ++k) v[k] = SA[tid + (k << 8)];
        dft8<-1>(v);
        #pragma unroll
        for (int m = 1; m < 8; ++m) v[m] = cmul(v[m], TWs1[(m << 8) + tid]);
        #pragma unroll
        for (int m = 0; m < 8; ++m) SA[tid + (m << 8)] = v[m];
        __syncthreads();

        // F2
        {
            int c = tid >> 5, j2 = tid & 31;
            int base = (c << 8) + j2;
            #pragma unroll
            for (int k = 0; k < 8; ++k) v[k] = SA[base + (k << 5)];
            dft8<-1>(v);
            #pragma unroll
            for (int m = 1; m < 8; ++m) v[m] = cmul(v[m], TWs2[(m << 5) + j2]);
            __syncthreads();
            #pragma unroll
            for (int m = 0; m < 8; ++m) SA[(c << 8) + (m << 5) + (j2 ^ (m << 2))] = v[m];
        }
        __syncthreads();

        // F3 + F4(quad) + mask + I1(quad) + I2
        {
            int bb = tid >> 2, j = tid & 3;
            int base = bb << 5, bx = (bb & 7) << 2;
            #pragma unroll
            for (int k = 0; k < 8; ++k) v[k] = SA[base + ((k << 2) ^ bx) + j];
            dft8<-1>(v);
            #pragma unroll
            for (int m = 1; m < 8; ++m) v[m] = cmul(v[m], TWs3[(m << 2) + j]);
            #pragma unroll
            for (int m = 0; m < 8; ++m) {
                c2 w = v[m];
                c2 p = shx(w, 2);
                c2 e  = (j & 2) ? csub(p, w) : cadd(w, p);
                c2 qq = shx(e, 1);
                c2 lo = (j & 1) ? csub(qq, e) : cadd(e, qq);
                c2 hi = (j & 1) ? make_float2(qq.x - e.y, qq.y + e.x)
                                : make_float2(e.x + qq.y, e.y - qq.x);
                w = (j & 2) ? hi : lo;
                float mk = MKs[(m << 8) + tid];
                w.x *= mk; w.y *= mk;
                c2 p2 = shx(w, 1);
                c2 e2 = (j & 1) ? csub(p2, w) : cadd(w, p2);
                c2 q2 = shx(e2, 2);
                c2 lo2 = (j & 1) ? make_float2(e2.x - q2.y, e2.y + q2.x)
                                 : cadd(e2, q2);
                c2 hi2 = (j & 1) ? make_float2(q2.x + e2.y, q2.y - e2.x)
                                 : csub(q2, e2);
                v[m] = (j & 2) ? hi2 : lo2;
            }
            #pragma unroll
            for (int m = 1; m < 8; ++m) v[m] = cmulj(v[m], TWs3[(m << 2) + j]);
            dft8<+1>(v);
            __syncthreads();
            #pragma unroll
            for (int k = 0; k < 8; ++k) SA[base + ((k << 2) ^ bx) + j] = v[k];
        }
        __syncthreads();

        // I3
        {
            int c = tid >> 5, j2 = tid & 31;
            #pragma unroll
            for (int m = 0; m < 8; ++m) v[m] = SA[(c << 8) + (m << 5) + (j2 ^ (m << 2))];
            #pragma unroll
            for (int m = 1; m < 8; ++m) v[m] = cmulj(v[m], TWs2[(m << 5) + j2]);
            dft8<+1>(v);
            __syncthreads();
            #pragma unroll
            for (int k = 0; k < 8; ++k) SA[(c << 8) + (k << 5) + j2] = v[k];
        }
        __syncthreads();

        // I4 -> OLA ring
        {
            #pragma unroll
            for (int m = 0; m < 8; ++m) v[m] = SA[tid + (m << 8)];
            #pragma unroll
            for (int m = 1; m < 8; ++m) v[m] = cmulj(v[m], TWs1[(m << 8) + tid]);
            dft8<+1>(v);
            #pragma unroll
            for (int k = 0; k < 8; ++k) {
                float w = WN[tid + (k << 8)];
                ring[k].x += v[k].x * w;
                ring[k].y += v[k].y * w;
            }
        }
        __syncthreads();

        if (t >= cmin) emit_chunk(dst, WN, t, tid, ring[0], ring[1]);
        #pragma unroll
        for (int q = 0; q < 6; ++q) ring[q] = ring[q + 2];
        ring[6] = make_float2(0.0f, 0.0f);
        ring[7] = make_float2(0.0f, 0.0f);
    }
    for (int c = t1 + 1; c <= cmax; ++c) {
        emit_chunk(dst, WN, c, tid, ring[0], ring[1]);
        #pragma unroll
        for (int q = 0; q < 6; ++q) ring[q] = ring[q + 2];
        ring[6] = make_float2(0.0f, 0.0f);
        ring[7] = make_float2(0.0f, 0.0f);
    }
}

__device__ __forceinline__ float gaval(float v, float thr, float coef) {
    float aa = fabsf(v) + 1e-8f;
    return fmaxf(6.020599913279624f * __log2f(aa) - thr, 0.0f) * coef;
}

// ---------- producer: K=3 composed records (exact DP), transposed layout ----------
// Record r of segment s composes samples li=s*SEG+3r..+2 into intercepts I0..I3 with
// global slopes S_j = A^(3-j) B^j :  p' = max_j(S_j*p + I_j)  == 3 exact reference steps.
__global__ __launch_bounds__(256) void triple_kernel(
    const float* __restrict__ y, float4* __restrict__ rec,
    const float* __restrict__ thr_p, const float* __restrict__ ratio_p,
    const float* __restrict__ att_p, const float* __restrict__ rel_p)
{
    __shared__ float4 L[64][33];
    const int r0 = blockIdx.x * 32;
    const int s0 = blockIdx.y * 64;
    const int c  = blockIdx.z;
    const int tid = threadIdx.x;

    float thr = *thr_p, ratio = *ratio_p;
    float A  = expf(-1.0f / ((*att_p) * 48000.0f));
    float Bc = expf(-1.0f / ((*rel_p) * 48000.0f));
    float ra = (1.0f - Bc) / (1.0f - A);
    float coef = (1.0f - 1.0f / ratio) * (1.0f - A);

    const int rr = tid & 31;
    #pragma unroll 1
    for (int it = 0; it < 8; ++it) {
        int ss = (tid >> 5) + it * 8;
        int s = s0 + ss;
        if (s < NSEG) {
            int li = s * SEG + 3 * (r0 + rr);
            const float* yp = y + c * T_LEN + li;
            float a1 = gaval(yp[0], thr, coef);
            float a2 = gaval(yp[1], thr, coef);
            float a3 = gaval(yp[2], thr, coef);
            if (li == 0) a1 = 0.0f;
            float b2 = ra * a2, b3 = ra * a3;
            float C0 = a1, C1 = ra * a1;
            float D0 = fmaf(A, C0, a2);
            float D1 = fmaxf(fmaf(A, C1, a2), fmaf(Bc, C0, b2));
            float D2 = fmaf(Bc, C1, b2);
            float I0 = fmaf(A, D0, a3);
            float I1 = fmaxf(fmaf(A, D1, a3), fmaf(Bc, D0, b3));
            float I2 = fmaxf(fmaf(A, D2, a3), fmaf(Bc, D1, b3));
            float I3 = fmaf(Bc, D2, b3);
            L[ss][rr] = make_float4(I0, I1, I2, I3);
        }
    }
    __syncthreads();
    const int cc = tid & 63;
    #pragma unroll 1
    for (int it = 0; it < 8; ++it) {
        int rr2 = (tid >> 6) + it * 4;
        if (s0 + cc < NSEG)
            rec[(long)c * PLANE + (r0 + rr2) * RST + 4 + s0 + cc] = L[cc][rr2];
    }
}

// zero the 4 warm-up pad columns (ws is poisoned 0xAA each call)
__global__ __launch_bounds__(256) void padzero_kernel(float4* __restrict__ rec)
{
    int idx = blockIdx.x * 256 + threadIdx.x;
    if (idx >= 2 * RECS * 4) return;
    int ch = idx / (RECS * 4);
    int r  = (idx >> 2) % RECS;
    int colp = idx & 3;
    rec[(long)ch * PLANE + r * RST + colp] = make_float4(0.f, 0.f, 0.f, 0.f);
}

// ---------- scan: one pass down one column, 16-record double-buffered ----------
template<bool STORE>
__device__ void scan_pass(const float4* __restrict__ cp, float* __restrict__ sp,
                          float& p, float S0, float S1, float S2, float S3)
{
    float4 bA[16], bB[16];
    #pragma unroll
    for (int k = 0; k < 16; ++k) bA[k] = cp[k * RST];
    __builtin_amdgcn_sched_barrier(0);
    int r = 0;
    #pragma unroll 1
    for (int gg = 0; gg < 80; ++gg) {
        #pragma unroll
        for (int k = 0; k < 16; ++k) bB[k] = cp[(r + 16 + k) * RST];
        __builtin_amdgcn_sched_barrier(0);
        #pragma unroll
        for (int k = 0; k < 16; ++k) {
            float4 v = bA[k];
            float t0 = fmaf(S0, p, v.x), t1 = fmaf(S1, p, v.y);
            float t2 = fmaf(S2, p, v.z), t3 = fmaf(S3, p, v.w);
            p = fmaxf(fmaxf(t0, t1), fmaxf(t2, t3));
            if (STORE) sp[(r + k) * RST] = p;
        }
        __builtin_amdgcn_sched_barrier(0);
        #pragma unroll
        for (int k = 0; k < 16; ++k) bA[k] = cp[(r + 32 + k) * RST];  // junk rows past 2559: discarded
        __builtin_amdgcn_sched_barrier(0);
        #pragma unroll
        for (int k = 0; k < 16; ++k) {
            float4 v = bB[k];
            float t0 = fmaf(S0, p, v.x), t1 = fmaf(S1, p, v.y);
            float t2 = fmaf(S2, p, v.z), t3 = fmaf(S3, p, v.w);
            p = fmaxf(fmaxf(t0, t1), fmaxf(t2, t3));
            if (STORE) sp[(r + 16 + k) * RST] = p;
        }
        __builtin_amdgcn_sched_barrier(0);
        r += 32;
    }
}

// lane = segment; cols s..s+3 = warm (4 segs = 30720 samples, pads make s<4 exact),
// col s+4 = own segment (stores state per record to gsP, coalesced across lanes).
__global__ __launch_bounds__(64, 1) void scan_kernel(
    const float4* __restrict__ rec, float* __restrict__ gsP,
    const float* __restrict__ att_p, const float* __restrict__ rel_p)
{
    int gid = blockIdx.x * 64 + threadIdx.x;
    int g2 = min(gid, 2 * NSEG - 1);
    int c = g2 / NSEG;
    int s = g2 - c * NSEG;

    float A  = expf(-1.0f / ((*att_p) * 48000.0f));
    float Bc = expf(-1.0f / ((*rel_p) * 48000.0f));
    float S0 = A * A * A, S1 = A * A * Bc, S2 = A * Bc * Bc, S3 = Bc * Bc * Bc;

    const float4* cbase = rec + (long)c * PLANE + s;
    float* sbase = gsP + (long)c * SPLANE + 4 + s;
    float p = 0.0f;

    #pragma unroll 1
    for (int j = 0; j < 4; ++j)
        scan_pass<false>(cbase + j, nullptr, p, S0, S1, S2, S3);
    scan_pass<true>(cbase + 4, sbase, p, S0, S1, S2, S3);
}

// ---------- final: LDS-transposed state tile + exact per-sample reconstruction ----------
__global__ __launch_bounds__(256) void final_kernel(
    const float* __restrict__ y, const float* __restrict__ gsP, float* __restrict__ out,
    const float* __restrict__ thr_p, const float* __restrict__ ratio_p,
    const float* __restrict__ att_p, const float* __restrict__ rel_p,
    const float* __restrict__ mk_p, const float* __restrict__ sat_p)
{
    __shared__ float LP[64][34];
    const int r0 = blockIdx.x * 32;
    const int s0 = blockIdx.y * 64;
    const int c  = blockIdx.z;
    const int tid = threadIdx.x;

    float thr = *thr_p, ratio = *ratio_p, mk = *mk_p, sat = *sat_p;
    float A  = expf(-1.0f / ((*att_p) * 48000.0f));
    float Bc = expf(-1.0f / ((*rel_p) * 48000.0f));
    float ra = (1.0f - Bc) / (1.0f - A);
    float coef = (1.0f - 1.0f / ratio) * (1.0f - A);
    const float* gb = gsP + (long)c * SPLANE;

    // rows r0-1 .. r0+31 (33) x 64 cols; LP[ss][rr] = state at record row r0-1+rr
    for (int idx = tid; idx < 33 * 64; idx += 256) {
        int rr = idx >> 6, ss = idx & 63;
        int s = s0 + ss;
        float v = 0.0f;
        if (s < NSEG) {
            int row = r0 - 1 + rr;
            if (row >= 0)      v = gb[row * RST + 4 + s];
            else if (s > 0)    v = gb[(RECS - 1) * RST + 4 + s - 1];
            // else s==0,row<0 -> true initial state 0
        }
        LP[ss][rr] = v;
    }
    __syncthreads();

    #pragma unroll 1
    for (int it = 0; it < 8; ++it) {
        int idx = it * 256 + tid;
        int ss = idx >> 5, rr = idx & 31;
        int s = s0 + ss;
        if (s >= NSEG) continue;
        int r = r0 + rr;
        int li = s * SEG + 3 * r;
        const float* yp = y + c * T_LEN + li;
        float* op = out + c * T_LEN + li;
        float p = LP[ss][rr];
        float y0 = yp[0], y1 = yp[1], y2 = yp[2];
        #pragma unroll
        for (int q = 0; q < 3; ++q) {
            float v = (q == 0) ? y0 : ((q == 1) ? y1 : y2);
            float a = gaval(v, thr, coef);
            if (li + q == 0) a = 0.0f;
            p = fmaxf(fmaf(A, p, a), fmaf(Bc, p, ra * a));
            float aa = fabsf(v) + 1e-8f;
            float gl = exp2f((mk - p) * 0.16609640474436813f);
            float ro = aa * gl;
            ro = (v < 0.0f) ? -ro : ro;
            if (sat > 1.0f) ro = tanhf(ro * sat) / sat;
            op[q] = ro;
        }
    }
}

extern "C" void kernel_launch(void* const* d_in, const int* in_sizes, int n_in,
                              void* d_out, int out_size, void* d_ws, size_t ws_size,
                              hipStream_t stream)
{
    const float* audio = (const float*)d_in[0];
    const float* g1    = (const float*)d_in[1];
    const float* g2    = (const float*)d_in[2];
    const float* g3    = (const float*)d_in[3];
    const float* g4    = (const float*)d_in[4];
    const float* thr   = (const float*)d_in[5];
    const float* ratio = (const float*)d_in[6];
    const float* att   = (const float*)d_in[7];
    const float* rel   = (const float*)d_in[8];
    const float* mkup  = (const float*)d_in[9];
    const float* sat   = (const float*)d_in[10];

    float* out  = (float*)d_out;                       // EQ ping-pong; final output
    float* bufA = (float*)d_ws;                        // 23.04 MB
    float4* rec = (float4*)(bufA + 2 * T_LEN);         // 2*PLANE float4 = 31.7 MB
    float*  gsP = (float*)(rec + 2 * (long)PLANE);     // 2*SPLANE float = 7.9 MB

    eq_band_kernel<<<NBLK_EQ, 256, 0, stream>>>(audio, out,  g1, 100.0f);
    eq_band_kernel<<<NBLK_EQ, 256, 0, stream>>>(out,   bufA, g2, 500.0f);
    eq_band_kernel<<<NBLK_EQ, 256, 0, stream>>>(bufA,  out,  g3, 3000.0f);
    eq_band_kernel<<<NBLK_EQ, 256, 0, stream>>>(out,   bufA, g4, 10000.0f);

    padzero_kernel<<<(2 * RECS * 4 + 255) / 256, 256, 0, stream>>>(rec);
    dim3 tgrid(RECS / 32, (NSEG + 63) / 64, 2);        // 80 x 6 x 2
    triple_kernel<<<tgrid, 256, 0, stream>>>(bufA, rec, thr, ratio, att, rel);
    scan_kernel<<<12, 64, 0, stream>>>(rec, gsP, att, rel);
    final_kernel<<<tgrid, 256, 0, stream>>>(bufA, gsP, out,
                                            thr, ratio, att, rel, mkup, sat);
}